// Round 8
// baseline (116.889 us; speedup 1.0000x reference)
//
#include <hip/hip_runtime.h>
#include <hip/hip_bf16.h>

// MatcherSimple — batched rectangular LSA (JV shortest augmenting path).
// B=8, P=4096 cols (proposals), G=96 rows (GT). cost = center_dist - 2*gious.
// Round 8 (polish): R7 structure + nontemporal stores for costT/partial and
// NT loads for the read-once cd/gi streams (cheaper inter-kernel L2 drain),
// + waves 1-3 warm L2 with the first scan row of each pending augmentation.
// Solver semantics identical to R3..R7 (absmax=0 validated each round).

#define P_N 4096
#define G_M 96
#define BIGF 1e9f
#define NSTRIPE 64

__device__ __forceinline__ void lexmin(float& bv, int& bi, float ov, int oi) {
    if (ov < bv || (ov == bv && oi < bi)) { bv = ov; bi = oi; }
}
__device__ __forceinline__ unsigned int ord32(float f) {
    unsigned int u = __float_as_uint(f);
    return u ^ ((unsigned int)((int)u >> 31) | 0x80000000u);
}
__device__ __forceinline__ float unord32(unsigned int k) {
    unsigned int u = (k & 0x80000000u) ? (k ^ 0x80000000u) : ~k;
    return __uint_as_float(u);
}

// fast 64-lane min reductions (validated R5..R7)
#define DPP_I(x, ctrl) __builtin_amdgcn_update_dpp(x, x, ctrl, 0xF, 0xF, false)
__device__ __forceinline__ float wave_min_f32(float x) {
    x = fminf(x, __int_as_float(DPP_I(__float_as_int(x), 0xB1)));
    x = fminf(x, __int_as_float(DPP_I(__float_as_int(x), 0x4E)));
    x = fminf(x, __int_as_float(DPP_I(__float_as_int(x), 0x141)));
    x = fminf(x, __int_as_float(DPP_I(__float_as_int(x), 0x140)));
    x = fminf(x, __int_as_float(__builtin_amdgcn_ds_swizzle(__float_as_int(x), 0x401F)));
    x = fminf(x, __shfl_xor(x, 32, 64));
    return x;
}
__device__ __forceinline__ int wave_min_i32(int x) {
    x = min(x, DPP_I(x, 0xB1));
    x = min(x, DPP_I(x, 0x4E));
    x = min(x, DPP_I(x, 0x141));
    x = min(x, DPP_I(x, 0x140));
    x = min(x, __builtin_amdgcn_ds_swizzle(x, 0x401F));
    x = min(x, __shfl_xor(x, 32, 64));
    return x;
}

// ---- cost build + transpose + per-row per-stripe argmin (rows < nrows only)
__global__ __launch_bounds__(256) void cost_prep(
    const float* __restrict__ cd, const float* __restrict__ gi,
    const int* __restrict__ nactual,
    float* __restrict__ costT, unsigned long long* __restrict__ partial)
{
    __shared__ float tile[64][G_M + 1];
    const int b  = blockIdx.x >> 6;
    const int st = blockIdx.x & 63;
    const int pb = st * 64;
    const int nrows = nactual[b];
    if (nrows <= 0) return;

    const size_t base = ((size_t)b * P_N + pb) * G_M;
    for (int t = threadIdx.x; t < 64 * nrows; t += 256) {
        int p = t / nrows, g = t - p * nrows;
        size_t idx = base + (size_t)p * G_M + g;
        float a = __builtin_nontemporal_load(&cd[idx]);
        float q = __builtin_nontemporal_load(&gi[idx]);
        tile[p][g] = a - 2.0f * q;
    }
    __syncthreads();
    for (int t = threadIdx.x; t < nrows * 64; t += 256) {
        int g = t >> 6, p = t & 63;
        __builtin_nontemporal_store(tile[p][g],
            &costT[((size_t)b * G_M + g) * P_N + pb + p]);
    }
    if (threadIdx.x < nrows) {
        int g = threadIdx.x;
        float bv = tile[0][g]; int bp = pb;
        #pragma unroll 8
        for (int p = 1; p < 64; ++p) {
            float val = tile[p][g];
            if (val < bv) { bv = val; bp = pb + p; }  // strict: first occurrence
        }
        __builtin_nontemporal_store(
            ((unsigned long long)ord32(bv) << 32) | (unsigned int)bp,
            &partial[((size_t)b * NSTRIPE + st) * G_M + g]);
    }
}

// ---- JV solve: one block (4 waves) per batch; Dijkstra in wave 0 ----------
__global__ __launch_bounds__(256, 1) void lsa_solve(
    const float* __restrict__ costT,
    const unsigned long long* __restrict__ partial,
    const int* __restrict__ nactual,
    float* __restrict__ out, int B)
{
    const int b = blockIdx.x;
    const int tid = threadIdx.x;
    const int lane = tid & 63;
    const int wave = tid >> 6;

    __shared__ float shL[P_N];                 // 16 KB: claim ints, then shortest
    __shared__ unsigned int prL[P_N / 4];      // 4 KB: packed pathr (u8 x4)
    __shared__ short row4col[P_N];             // 8 KB
    __shared__ unsigned long long cand[4][G_M];// 3 KB: per-wave rowmin candidates
    __shared__ float u[G_M];
    __shared__ short col4row[G_M];
    __shared__ short argcL[G_M];
    __shared__ short pend[G_M];
    __shared__ int s_npend, s_sink, s_i;
    __shared__ float s_minval;
    __shared__ unsigned long long s_SR0, s_SR1;
    __shared__ float s_sinkhole;

    const int nrows = nactual[b];

    // block-wide LDS init
    #pragma unroll
    for (int k = 0; k < 4; ++k) {
        int c = k * 1024 + tid * 4;
        *(uint2*)&row4col[c] = make_uint2(0xFFFFFFFFu, 0xFFFFFFFFu);
        *(int4*)&shL[c] = make_int4(0x7FFFFFFF, 0x7FFFFFFF, 0x7FFFFFFF, 0x7FFFFFFF);
    }
    if (tid < G_M) col4row[tid] = -1;
    if (tid == 0) s_npend = 0;

    // staged partial-minima reduce: wave w covers stripes [w*16, w*16+16)
    if (nrows > 0) {
        const unsigned long long* pbase = partial + (size_t)b * NSTRIPE * G_M;
        unsigned long long b1 = ~0ull, b2 = ~0ull;
        #pragma unroll 4
        for (int s = 0; s < 16; ++s) {
            const unsigned long long* row = pbase + (size_t)(wave * 16 + s) * G_M;
            unsigned long long p1 = row[lane];
            if (p1 < b1) b1 = p1;
            if (lane < 32) {
                unsigned long long p2 = row[64 + lane];
                if (p2 < b2) b2 = p2;
            }
        }
        cand[wave][lane] = b1;
        if (lane < 32) cand[wave][64 + lane] = b2;
    }
    __syncthreads();
    if (wave == 0 && nrows > 0) {
        #pragma unroll
        for (int r0 = 0; r0 < G_M; r0 += 64) {
            int r = r0 + lane;
            if (r < G_M) {
                unsigned long long best = cand[0][r];
                if (cand[1][r] < best) best = cand[1][r];
                if (cand[2][r] < best) best = cand[2][r];
                if (cand[3][r] < best) best = cand[3][r];
                u[r] = unord32((unsigned int)(best >> 32));
                argcL[r] = (short)(best & 0xFFFFull);
            }
        }
    }
    __syncthreads();

    // parallel greedy claim: lowest row index wins (== serial scipy order)
    int* claim = (int*)shL;
    const int r1 = lane, r2 = 64 + lane;
    const bool a1 = (wave == 0) && (r1 < nrows);
    const bool a2 = (wave == 0) && (r2 < G_M) && (r2 < nrows);
    const int j1 = a1 ? argcL[r1] : 0, j2 = a2 ? argcL[r2] : 0;
    if (a1) atomicMin(&claim[j1], r1);
    if (a2) atomicMin(&claim[j2], r2);
    __syncthreads();
    if (wave == 0) {
        const bool w1 = a1 && (*(volatile int*)&claim[j1] == r1);
        const bool w2 = a2 && (*(volatile int*)&claim[j2] == r2);
        unsigned long long l1 = __ballot(a1 && !w1);
        unsigned long long l2 = __ballot(a2 && !w2);
        if (w1) { row4col[j1] = (short)r1; col4row[r1] = (short)j1; }
        if (w2) { row4col[j2] = (short)r2; col4row[r2] = (short)j2; }
        const int n1 = __popcll(l1);
        const unsigned long long below = (1ull << lane) - 1;
        if (a1 && !w1) pend[__popcll(l1 & below)] = (short)r1;
        if (a2 && !w2) pend[n1 + __popcll(l2 & below)] = (short)r2;
        if (lane == 0) s_npend = n1 + __popcll(l2);
    }
    __syncthreads();
    const int npend = s_npend;

    // waves 1-3: warm L2 with the first scan row of pending augmentations
    if (wave > 0 && (wave - 1) < npend) {
        const int rw = pend[wave - 1];
        const float4* crow4 = (const float4*)(costT + ((size_t)b * G_M + rw) * P_N);
        float acc = 0.f;
        #pragma unroll
        for (int k = 0; k < 16; ++k) {
            float4 cc = crow4[k * 64 + lane];
            acc = fminf(acc, fminf(fminf(cc.x, cc.y), fminf(cc.z, cc.w)));
        }
        if (acc == -1.2345678e33f) s_sinkhole = acc;  // keep loads live; never true
    }

    // per-lane register state for owned cols (lane owns k*256+lane*4+q)
    float4 vr[16], shr[16];
    unsigned int pr[16];
    unsigned long long scm = 0;
    const float4 BIG4 = make_float4(BIGF, BIGF, BIGF, BIGF);
    #pragma unroll
    for (int k = 0; k < 16; ++k) {
        vr[k] = make_float4(0.f, 0.f, 0.f, 0.f);
        shr[k] = BIG4; pr[k] = 0u;
    }

    // Dijkstra augmentation for leftover rows (wave 0 scans; barriers A-D)
    for (int pi = 0; pi < npend; ++pi) {
        if (wave == 0) {
            const int i = pend[pi];
            float minval = 0.0f;
            int cur = i, sink = -1;
            unsigned long long SR0 = 0, SR1 = 0;

            for (int guard = 0; guard <= P_N; ++guard) {
                if (cur < 64) SR0 |= 1ull << cur; else SR1 |= 1ull << (cur - 64);
                const float ucur = u[cur];                    // LDS broadcast
                const float4* crow4 =
                    (const float4*)(costT + ((size_t)b * G_M + cur) * P_N);

                float bv = 3.0e38f; int bi = P_N;
                #pragma unroll
                for (int k = 0; k < 16; ++k) {
                    const float4 cc = crow4[k * 64 + lane];
                    float4 sh = shr[k];
                    const float4 vv = vr[k];
                    const unsigned int mb = (unsigned int)(scm >> (k * 4)) & 0xFu;
                    float q0 = ((minval + cc.x) - ucur) - vv.x;
                    float q1 = ((minval + cc.y) - ucur) - vv.y;
                    float q2 = ((minval + cc.z) - ucur) - vv.z;
                    float q3 = ((minval + cc.w) - ucur) - vv.w;
                    const bool u0 = !(mb & 1u), u1 = !(mb & 2u);
                    const bool u2 = !(mb & 4u), u3 = !(mb & 8u);
                    if (u0 && q0 < sh.x) { sh.x = q0; pr[k] = (pr[k] & 0xFFFFFF00u) | (unsigned)cur; }
                    if (u1 && q1 < sh.y) { sh.y = q1; pr[k] = (pr[k] & 0xFFFF00FFu) | ((unsigned)cur << 8); }
                    if (u2 && q2 < sh.z) { sh.z = q2; pr[k] = (pr[k] & 0xFF00FFFFu) | ((unsigned)cur << 16); }
                    if (u3 && q3 < sh.w) { sh.w = q3; pr[k] = (pr[k] & 0x00FFFFFFu) | ((unsigned)cur << 24); }
                    shr[k] = sh;
                    const int cbase = k * 256 + lane * 4;
                    lexmin(bv, bi, u0 ? sh.x : BIGF, cbase + 0);
                    lexmin(bv, bi, u1 ? sh.y : BIGF, cbase + 1);
                    lexmin(bv, bi, u2 ? sh.z : BIGF, cbase + 2);
                    lexmin(bv, bi, u3 ? sh.w : BIGF, cbase + 3);
                }
                const float gv = wave_min_f32(bv);
                const int gidx = wave_min_i32(bv == gv ? bi : 0x7FFFFFFF);
                minval = gv;
                if (gidx >= P_N) { sink = -2; break; }        // no-hang guard
                if (((gidx >> 2) & 63) == lane)               // owner sets SC bit
                    scm |= 1ull << (((gidx >> 8) << 2) | (gidx & 3));
                const int r = row4col[gidx];                  // LDS broadcast
                if (r < 0) { sink = gidx; break; }
                cur = r;
            }
            if (lane == 0) {
                s_sink = sink; s_minval = minval; s_i = i;
                s_SR0 = SR0; s_SR1 = SR1;
            }
        }
        __syncthreads();                                       // A
        const int sink = s_sink;
        const float minval = s_minval;
        const int i = s_i;

        if (wave == 0 && sink >= 0) {     // write back shortest + pathr
            #pragma unroll
            for (int k = 0; k < 16; ++k) {
                const int c = k * 256 + lane * 4;
                *(float4*)&shL[c] = shr[k];
                prL[k * 64 + lane] = pr[k];
            }
        }
        __syncthreads();                                       // B
        if (sink >= 0 && tid < G_M) {     // dual u updates (pre-augment col4row)
            const bool sr = (tid < 64) ? ((s_SR0 >> tid) & 1ull)
                                       : ((s_SR1 >> (tid - 64)) & 1ull);
            if (tid == i) u[tid] = u[tid] + minval;
            else if (sr) {
                int c4 = col4row[tid]; if (c4 < 0) c4 = 0;
                u[tid] = (u[tid] + minval) - shL[c4];
            }
        }
        __syncthreads();                                       // C
        if (wave == 0 && sink >= 0) {     // v update + register state reset
            #pragma unroll
            for (int k = 0; k < 16; ++k) {
                const unsigned int mb = (unsigned int)(scm >> (k * 4)) & 0xFu;
                float4 vv = vr[k];
                const float4 sh = shr[k];
                if (mb & 1u) vv.x -= minval - sh.x;
                if (mb & 2u) vv.y -= minval - sh.y;
                if (mb & 4u) vv.z -= minval - sh.z;
                if (mb & 8u) vv.w -= minval - sh.w;
                vr[k] = vv;
                shr[k] = BIG4;
            }
            scm = 0;
            if (lane == 0) {              // augment: flip alternating path
                int j = sink;
                for (int g2 = 0; g2 < G_M + 2; ++g2) {
                    int r = (int)((prL[j >> 2] >> (8 * (j & 3))) & 0xFFu);
                    row4col[j] = (short)r;
                    int jn = col4row[r];
                    col4row[r] = (short)j;
                    if (r == i) break;
                    j = jn;
                }
            }
        }
        __syncthreads();                                       // D
    }

    // outputs: inds then mask, each [B, P], float4-vectorized, all 256 threads
    float* out_inds = out + (size_t)b * P_N;
    float* out_mask = out + (size_t)B * P_N + (size_t)b * P_N;
    #pragma unroll
    for (int k = 0; k < 4; ++k) {
        int c = k * 1024 + tid * 4;
        uint2 rr = *(const uint2*)&row4col[c];
        short q0 = (short)(rr.x & 0xFFFFu), q1 = (short)(rr.x >> 16);
        short q2 = (short)(rr.y & 0xFFFFu), q3 = (short)(rr.y >> 16);
        float4 fi, fm;
        fi.x = q0 >= 0 ? (float)q0 : 0.f;  fm.x = q0 >= 0 ? 1.f : 0.f;
        fi.y = q1 >= 0 ? (float)q1 : 0.f;  fm.y = q1 >= 0 ? 1.f : 0.f;
        fi.z = q2 >= 0 ? (float)q2 : 0.f;  fm.z = q2 >= 0 ? 1.f : 0.f;
        fi.w = q3 >= 0 ? (float)q3 : 0.f;  fm.w = q3 >= 0 ? 1.f : 0.f;
        *(float4*)&out_inds[c] = fi;
        *(float4*)&out_mask[c] = fm;
    }
}

// ---- fallback: round-1 full-sweep LSA (only if workspace too small) -------
#define BLK 1024
#define WAVES (BLK / 64)
__global__ __launch_bounds__(BLK) void lsa_full(
    const float* __restrict__ cd, const float* __restrict__ gi,
    const int* __restrict__ nactual,
    float* __restrict__ out, int B)
{
    const int b = blockIdx.x, tid = threadIdx.x;
    __shared__ float v[P_N];
    __shared__ float shortest[P_N];
    __shared__ short path[P_N];
    __shared__ short row4col[P_N];
    __shared__ unsigned char SC[P_N];
    __shared__ float u[G_M];
    __shared__ short col4row[G_M];
    __shared__ unsigned char SR[G_M];
    __shared__ float s_minval;
    __shared__ int s_j, s_cur, s_done;
    __shared__ float rv[WAVES];
    __shared__ int ri[WAVES];

    for (int j = tid; j < P_N; j += BLK) { v[j] = 0.0f; row4col[j] = -1; }
    if (tid < G_M) { u[tid] = 0.0f; col4row[tid] = -1; }
    const int nrows = nactual[b];
    __syncthreads();

    for (int i = 0; i < nrows; ++i) {
        for (int j = tid; j < P_N; j += BLK) { shortest[j] = BIGF; path[j] = -1; SC[j] = 0; }
        if (tid < G_M) SR[tid] = 0;
        if (tid == 0) s_done = 0;
        __syncthreads();
        float minval = 0.0f; int cur = i, sink = -1;
        while (true) {
            if (tid == 0) SR[cur] = 1;
            const float ucur = u[cur];
            #pragma unroll
            for (int k = 0; k < P_N / BLK; ++k) {
                int j = tid + k * BLK;
                if (!SC[j]) {
                    size_t idx = ((size_t)b * P_N + j) * G_M + cur;
                    float c = cd[idx] - 2.0f * gi[idx];
                    float red = ((minval + c) - ucur) - v[j];
                    if (red < shortest[j]) { shortest[j] = red; path[j] = (short)cur; }
                }
            }
            __syncthreads();
            float bv = 3.0e38f; int bi = P_N;
            #pragma unroll
            for (int k = 0; k < P_N / BLK; ++k) {
                int j = tid + k * BLK;
                lexmin(bv, bi, SC[j] ? BIGF : shortest[j], j);
            }
            #pragma unroll
            for (int off = 32; off > 0; off >>= 1) {
                float ov = __shfl_xor(bv, off, 64);
                int oi = __shfl_xor(bi, off, 64);
                lexmin(bv, bi, ov, oi);
            }
            if ((tid & 63) == 0) { rv[tid >> 6] = bv; ri[tid >> 6] = bi; }
            __syncthreads();
            if (tid == 0) {
                float mv = rv[0]; int mi = ri[0];
                for (int w = 1; w < WAVES; ++w) lexmin(mv, mi, rv[w], ri[w]);
                s_minval = mv; s_j = mi; SC[mi] = 1;
                int r = row4col[mi];
                if (r < 0) s_done = 1; else s_cur = r;
            }
            __syncthreads();
            minval = s_minval;
            if (s_done) { sink = s_j; break; }
            cur = s_cur;
        }
        if (tid < G_M) {
            if (tid == i) u[tid] += minval;
            else if (SR[tid]) {
                int c = col4row[tid]; if (c < 0) c = 0;
                u[tid] = (u[tid] + minval) - shortest[c];
            }
        }
        #pragma unroll
        for (int k = 0; k < P_N / BLK; ++k) {
            int j = tid + k * BLK;
            if (SC[j]) v[j] -= (minval - shortest[j]);
        }
        __syncthreads();
        if (tid == 0) {
            int j = sink;
            while (true) {
                int r = path[j];
                row4col[j] = (short)r;
                int jn = col4row[r];
                col4row[r] = (short)j;
                if (r == i) break;
                j = jn;
            }
        }
        __syncthreads();
    }
    float* out_inds = out + (size_t)b * P_N;
    float* out_mask = out + (size_t)B * P_N + (size_t)b * P_N;
    for (int j = tid; j < P_N; j += BLK) {
        int r = row4col[j];
        out_inds[j] = (r >= 0) ? (float)r : 0.0f;
        out_mask[j] = (r >= 0) ? 1.0f : 0.0f;
    }
}

extern "C" void kernel_launch(void* const* d_in, const int* in_sizes, int n_in,
                              void* d_out, int out_size, void* d_ws, size_t ws_size,
                              hipStream_t stream) {
    const float* cd = (const float*)d_in[0];
    const float* gi = (const float*)d_in[1];
    const int*   na = (const int*)d_in[2];
    float* out = (float*)d_out;
    const int B = in_sizes[2];   // 8

    const size_t costT_b = (size_t)B * G_M * P_N * sizeof(float);
    const size_t pm_b    = (size_t)B * NSTRIPE * G_M * sizeof(unsigned long long);
    auto al = [](size_t x) { return (x + 255) & ~(size_t)255; };
    const size_t o1 = al(costT_b);
    const size_t need = o1 + al(pm_b);

    if (ws_size >= need) {
        float* costT = (float*)d_ws;
        unsigned long long* pm = (unsigned long long*)((char*)d_ws + o1);
        cost_prep<<<dim3(B * NSTRIPE), 256, 0, stream>>>(cd, gi, na, costT, pm);
        lsa_solve<<<dim3(B), 256, 0, stream>>>(costT, pm, na, out, B);
    } else {
        lsa_full<<<dim3(B), BLK, 0, stream>>>(cd, gi, na, out, B);
    }
}

// Round 9
// 102.204 us; speedup vs baseline: 1.1437x; 1.1437x over previous
//
#include <hip/hip_runtime.h>
#include <hip/hip_bf16.h>

// MatcherSimple — batched rectangular LSA (JV shortest augmenting path).
// B=8, P=4096 cols (proposals), G=96 rows (GT). cost = center_dist - 2*gious.
// Round 9 = exact revert to R7 (best: 102.9us).
// R6 lesson: per-block device fences = L2 writeback storms (~+50us).
// R8 lesson: NT stores evict the prep->solve working set from L2 (~+14us);
// the plain inter-kernel boundary keeps costT L2-resident for solve's scans.
//  - prep: only rows g < nactual[b] are transposed/argmin'd
//  - solve: 256 threads; coalesced partial-minima reduce; greedy claim
//    (lowest-row-wins == scipy serial order); Dijkstra in wave 0 with
//    register-resident state + DPP/swizzle wave argmin.
// Exact optimum unique w.p.1 for continuous costs => matches reference
// (absmax=0 validated R3..R8).

#define P_N 4096
#define G_M 96
#define BIGF 1e9f
#define NSTRIPE 64

__device__ __forceinline__ void lexmin(float& bv, int& bi, float ov, int oi) {
    if (ov < bv || (ov == bv && oi < bi)) { bv = ov; bi = oi; }
}
__device__ __forceinline__ unsigned int ord32(float f) {
    unsigned int u = __float_as_uint(f);
    return u ^ ((unsigned int)((int)u >> 31) | 0x80000000u);
}
__device__ __forceinline__ float unord32(unsigned int k) {
    unsigned int u = (k & 0x80000000u) ? (k ^ 0x80000000u) : ~k;
    return __uint_as_float(u);
}

// fast 64-lane min reductions (validated R5..R7)
#define DPP_I(x, ctrl) __builtin_amdgcn_update_dpp(x, x, ctrl, 0xF, 0xF, false)
__device__ __forceinline__ float wave_min_f32(float x) {
    x = fminf(x, __int_as_float(DPP_I(__float_as_int(x), 0xB1)));
    x = fminf(x, __int_as_float(DPP_I(__float_as_int(x), 0x4E)));
    x = fminf(x, __int_as_float(DPP_I(__float_as_int(x), 0x141)));
    x = fminf(x, __int_as_float(DPP_I(__float_as_int(x), 0x140)));
    x = fminf(x, __int_as_float(__builtin_amdgcn_ds_swizzle(__float_as_int(x), 0x401F)));
    x = fminf(x, __shfl_xor(x, 32, 64));
    return x;
}
__device__ __forceinline__ int wave_min_i32(int x) {
    x = min(x, DPP_I(x, 0xB1));
    x = min(x, DPP_I(x, 0x4E));
    x = min(x, DPP_I(x, 0x141));
    x = min(x, DPP_I(x, 0x140));
    x = min(x, __builtin_amdgcn_ds_swizzle(x, 0x401F));
    x = min(x, __shfl_xor(x, 32, 64));
    return x;
}

// ---- cost build + transpose + per-row per-stripe argmin (rows < nrows only)
__global__ __launch_bounds__(256) void cost_prep(
    const float* __restrict__ cd, const float* __restrict__ gi,
    const int* __restrict__ nactual,
    float* __restrict__ costT, unsigned long long* __restrict__ partial)
{
    __shared__ float tile[64][G_M + 1];
    const int b  = blockIdx.x >> 6;
    const int st = blockIdx.x & 63;
    const int pb = st * 64;
    const int nrows = nactual[b];
    if (nrows <= 0) return;

    const size_t base = ((size_t)b * P_N + pb) * G_M;
    for (int t = threadIdx.x; t < 64 * nrows; t += 256) {
        int p = t / nrows, g = t - p * nrows;
        size_t idx = base + (size_t)p * G_M + g;
        tile[p][g] = cd[idx] - 2.0f * gi[idx];
    }
    __syncthreads();
    for (int t = threadIdx.x; t < nrows * 64; t += 256) {
        int g = t >> 6, p = t & 63;
        costT[((size_t)b * G_M + g) * P_N + pb + p] = tile[p][g];
    }
    if (threadIdx.x < nrows) {
        int g = threadIdx.x;
        float bv = tile[0][g]; int bp = pb;
        #pragma unroll 8
        for (int p = 1; p < 64; ++p) {
            float val = tile[p][g];
            if (val < bv) { bv = val; bp = pb + p; }  // strict: first occurrence
        }
        partial[((size_t)b * NSTRIPE + st) * G_M + g] =
            ((unsigned long long)ord32(bv) << 32) | (unsigned int)bp;
    }
}

// ---- JV solve: one block (4 waves) per batch; Dijkstra in wave 0 ----------
__global__ __launch_bounds__(256, 1) void lsa_solve(
    const float* __restrict__ costT,
    const unsigned long long* __restrict__ partial,
    const int* __restrict__ nactual,
    float* __restrict__ out, int B)
{
    const int b = blockIdx.x;
    const int tid = threadIdx.x;
    const int lane = tid & 63;
    const int wave = tid >> 6;

    __shared__ float shL[P_N];                 // 16 KB: claim ints, then shortest
    __shared__ unsigned int prL[P_N / 4];      // 4 KB: packed pathr (u8 x4)
    __shared__ short row4col[P_N];             // 8 KB
    __shared__ unsigned long long cand[4][G_M];// 3 KB: per-wave rowmin candidates
    __shared__ float u[G_M];
    __shared__ short col4row[G_M];
    __shared__ short argcL[G_M];
    __shared__ short pend[G_M];
    __shared__ int s_npend, s_sink, s_i;
    __shared__ float s_minval;
    __shared__ unsigned long long s_SR0, s_SR1;

    const int nrows = nactual[b];

    // block-wide LDS init
    #pragma unroll
    for (int k = 0; k < 4; ++k) {
        int c = k * 1024 + tid * 4;
        *(uint2*)&row4col[c] = make_uint2(0xFFFFFFFFu, 0xFFFFFFFFu);
        *(int4*)&shL[c] = make_int4(0x7FFFFFFF, 0x7FFFFFFF, 0x7FFFFFFF, 0x7FFFFFFF);
    }
    if (tid < G_M) col4row[tid] = -1;
    if (tid == 0) s_npend = 0;

    // staged partial-minima reduce: wave w covers stripes [w*16, w*16+16)
    // (coalesced u64 loads; rows >= nrows hold ws-poison, unused)
    if (nrows > 0) {
        const unsigned long long* pbase = partial + (size_t)b * NSTRIPE * G_M;
        unsigned long long b1 = ~0ull, b2 = ~0ull;
        #pragma unroll 4
        for (int s = 0; s < 16; ++s) {
            const unsigned long long* row = pbase + (size_t)(wave * 16 + s) * G_M;
            unsigned long long p1 = row[lane];
            if (p1 < b1) b1 = p1;
            if (lane < 32) {
                unsigned long long p2 = row[64 + lane];
                if (p2 < b2) b2 = p2;
            }
        }
        cand[wave][lane] = b1;
        if (lane < 32) cand[wave][64 + lane] = b2;
    }
    __syncthreads();
    if (wave == 0 && nrows > 0) {
        #pragma unroll
        for (int r0 = 0; r0 < G_M; r0 += 64) {
            int r = r0 + lane;
            if (r < G_M) {
                unsigned long long best = cand[0][r];
                if (cand[1][r] < best) best = cand[1][r];
                if (cand[2][r] < best) best = cand[2][r];
                if (cand[3][r] < best) best = cand[3][r];
                u[r] = unord32((unsigned int)(best >> 32));
                argcL[r] = (short)(best & 0xFFFFull);
            }
        }
    }
    __syncthreads();

    // parallel greedy claim: lowest row index wins (== serial scipy order)
    int* claim = (int*)shL;
    const int r1 = lane, r2 = 64 + lane;
    const bool a1 = (wave == 0) && (r1 < nrows);
    const bool a2 = (wave == 0) && (r2 < G_M) && (r2 < nrows);
    const int j1 = a1 ? argcL[r1] : 0, j2 = a2 ? argcL[r2] : 0;
    if (a1) atomicMin(&claim[j1], r1);
    if (a2) atomicMin(&claim[j2], r2);
    __syncthreads();
    if (wave == 0) {
        const bool w1 = a1 && (*(volatile int*)&claim[j1] == r1);
        const bool w2 = a2 && (*(volatile int*)&claim[j2] == r2);
        unsigned long long l1 = __ballot(a1 && !w1);
        unsigned long long l2 = __ballot(a2 && !w2);
        if (w1) { row4col[j1] = (short)r1; col4row[r1] = (short)j1; }
        if (w2) { row4col[j2] = (short)r2; col4row[r2] = (short)j2; }
        const int n1 = __popcll(l1);
        const unsigned long long below = (1ull << lane) - 1;  // lane 63: low-63 mask, ok
        if (a1 && !w1) pend[__popcll(l1 & below)] = (short)r1;
        if (a2 && !w2) pend[n1 + __popcll(l2 & below)] = (short)r2;
        if (lane == 0) s_npend = n1 + __popcll(l2);
    }
    __syncthreads();
    const int npend = s_npend;

    // per-lane register state for owned cols (lane owns k*256+lane*4+q)
    float4 vr[16], shr[16];
    unsigned int pr[16];
    unsigned long long scm = 0;
    const float4 BIG4 = make_float4(BIGF, BIGF, BIGF, BIGF);
    #pragma unroll
    for (int k = 0; k < 16; ++k) {
        vr[k] = make_float4(0.f, 0.f, 0.f, 0.f);
        shr[k] = BIG4; pr[k] = 0u;
    }

    // Dijkstra augmentation for leftover rows (wave 0 scans; barriers A-D)
    for (int pi = 0; pi < npend; ++pi) {
        if (wave == 0) {
            const int i = pend[pi];
            float minval = 0.0f;
            int cur = i, sink = -1;
            unsigned long long SR0 = 0, SR1 = 0;

            for (int guard = 0; guard <= P_N; ++guard) {
                if (cur < 64) SR0 |= 1ull << cur; else SR1 |= 1ull << (cur - 64);
                const float ucur = u[cur];                    // LDS broadcast
                const float4* crow4 =
                    (const float4*)(costT + ((size_t)b * G_M + cur) * P_N);

                float bv = 3.0e38f; int bi = P_N;
                #pragma unroll
                for (int k = 0; k < 16; ++k) {
                    const float4 cc = crow4[k * 64 + lane];
                    float4 sh = shr[k];
                    const float4 vv = vr[k];
                    const unsigned int mb = (unsigned int)(scm >> (k * 4)) & 0xFu;
                    float q0 = ((minval + cc.x) - ucur) - vv.x;
                    float q1 = ((minval + cc.y) - ucur) - vv.y;
                    float q2 = ((minval + cc.z) - ucur) - vv.z;
                    float q3 = ((minval + cc.w) - ucur) - vv.w;
                    const bool u0 = !(mb & 1u), u1 = !(mb & 2u);
                    const bool u2 = !(mb & 4u), u3 = !(mb & 8u);
                    if (u0 && q0 < sh.x) { sh.x = q0; pr[k] = (pr[k] & 0xFFFFFF00u) | (unsigned)cur; }
                    if (u1 && q1 < sh.y) { sh.y = q1; pr[k] = (pr[k] & 0xFFFF00FFu) | ((unsigned)cur << 8); }
                    if (u2 && q2 < sh.z) { sh.z = q2; pr[k] = (pr[k] & 0xFF00FFFFu) | ((unsigned)cur << 16); }
                    if (u3 && q3 < sh.w) { sh.w = q3; pr[k] = (pr[k] & 0x00FFFFFFu) | ((unsigned)cur << 24); }
                    shr[k] = sh;
                    const int cbase = k * 256 + lane * 4;
                    lexmin(bv, bi, u0 ? sh.x : BIGF, cbase + 0);
                    lexmin(bv, bi, u1 ? sh.y : BIGF, cbase + 1);
                    lexmin(bv, bi, u2 ? sh.z : BIGF, cbase + 2);
                    lexmin(bv, bi, u3 ? sh.w : BIGF, cbase + 3);
                }
                const float gv = wave_min_f32(bv);
                const int gidx = wave_min_i32(bv == gv ? bi : 0x7FFFFFFF);
                minval = gv;
                if (gidx >= P_N) { sink = -2; break; }        // no-hang guard
                if (((gidx >> 2) & 63) == lane)               // owner sets SC bit
                    scm |= 1ull << (((gidx >> 8) << 2) | (gidx & 3));
                const int r = row4col[gidx];                  // LDS broadcast
                if (r < 0) { sink = gidx; break; }
                cur = r;
            }
            if (lane == 0) {
                s_sink = sink; s_minval = minval; s_i = i;
                s_SR0 = SR0; s_SR1 = SR1;
            }
        }
        __syncthreads();                                       // A
        const int sink = s_sink;
        const float minval = s_minval;
        const int i = s_i;

        if (wave == 0 && sink >= 0) {     // write back shortest + pathr
            #pragma unroll
            for (int k = 0; k < 16; ++k) {
                const int c = k * 256 + lane * 4;
                *(float4*)&shL[c] = shr[k];
                prL[k * 64 + lane] = pr[k];
            }
        }
        __syncthreads();                                       // B
        if (sink >= 0 && tid < G_M) {     // dual u updates (pre-augment col4row)
            const bool sr = (tid < 64) ? ((s_SR0 >> tid) & 1ull)
                                       : ((s_SR1 >> (tid - 64)) & 1ull);
            if (tid == i) u[tid] = u[tid] + minval;
            else if (sr) {
                int c4 = col4row[tid]; if (c4 < 0) c4 = 0;
                u[tid] = (u[tid] + minval) - shL[c4];
            }
        }
        __syncthreads();                                       // C
        if (wave == 0 && sink >= 0) {     // v update + register state reset
            #pragma unroll
            for (int k = 0; k < 16; ++k) {
                const unsigned int mb = (unsigned int)(scm >> (k * 4)) & 0xFu;
                float4 vv = vr[k];
                const float4 sh = shr[k];
                if (mb & 1u) vv.x -= minval - sh.x;
                if (mb & 2u) vv.y -= minval - sh.y;
                if (mb & 4u) vv.z -= minval - sh.z;
                if (mb & 8u) vv.w -= minval - sh.w;
                vr[k] = vv;
                shr[k] = BIG4;
            }
            scm = 0;
            if (lane == 0) {              // augment: flip alternating path
                int j = sink;
                for (int g2 = 0; g2 < G_M + 2; ++g2) {
                    int r = (int)((prL[j >> 2] >> (8 * (j & 3))) & 0xFFu);
                    row4col[j] = (short)r;
                    int jn = col4row[r];
                    col4row[r] = (short)j;
                    if (r == i) break;
                    j = jn;
                }
            }
        }
        __syncthreads();                                       // D
    }

    // outputs: inds then mask, each [B, P], float4-vectorized, all 256 threads
    float* out_inds = out + (size_t)b * P_N;
    float* out_mask = out + (size_t)B * P_N + (size_t)b * P_N;
    #pragma unroll
    for (int k = 0; k < 4; ++k) {
        int c = k * 1024 + tid * 4;
        uint2 rr = *(const uint2*)&row4col[c];
        short q0 = (short)(rr.x & 0xFFFFu), q1 = (short)(rr.x >> 16);
        short q2 = (short)(rr.y & 0xFFFFu), q3 = (short)(rr.y >> 16);
        float4 fi, fm;
        fi.x = q0 >= 0 ? (float)q0 : 0.f;  fm.x = q0 >= 0 ? 1.f : 0.f;
        fi.y = q1 >= 0 ? (float)q1 : 0.f;  fm.y = q1 >= 0 ? 1.f : 0.f;
        fi.z = q2 >= 0 ? (float)q2 : 0.f;  fm.z = q2 >= 0 ? 1.f : 0.f;
        fi.w = q3 >= 0 ? (float)q3 : 0.f;  fm.w = q3 >= 0 ? 1.f : 0.f;
        *(float4*)&out_inds[c] = fi;
        *(float4*)&out_mask[c] = fm;
    }
}

// ---- fallback: round-1 full-sweep LSA (only if workspace too small) -------
#define BLK 1024
#define WAVES (BLK / 64)
__global__ __launch_bounds__(BLK) void lsa_full(
    const float* __restrict__ cd, const float* __restrict__ gi,
    const int* __restrict__ nactual,
    float* __restrict__ out, int B)
{
    const int b = blockIdx.x, tid = threadIdx.x;
    __shared__ float v[P_N];
    __shared__ float shortest[P_N];
    __shared__ short path[P_N];
    __shared__ short row4col[P_N];
    __shared__ unsigned char SC[P_N];
    __shared__ float u[G_M];
    __shared__ short col4row[G_M];
    __shared__ unsigned char SR[G_M];
    __shared__ float s_minval;
    __shared__ int s_j, s_cur, s_done;
    __shared__ float rv[WAVES];
    __shared__ int ri[WAVES];

    for (int j = tid; j < P_N; j += BLK) { v[j] = 0.0f; row4col[j] = -1; }
    if (tid < G_M) { u[tid] = 0.0f; col4row[tid] = -1; }
    const int nrows = nactual[b];
    __syncthreads();

    for (int i = 0; i < nrows; ++i) {
        for (int j = tid; j < P_N; j += BLK) { shortest[j] = BIGF; path[j] = -1; SC[j] = 0; }
        if (tid < G_M) SR[tid] = 0;
        if (tid == 0) s_done = 0;
        __syncthreads();
        float minval = 0.0f; int cur = i, sink = -1;
        while (true) {
            if (tid == 0) SR[cur] = 1;
            const float ucur = u[cur];
            #pragma unroll
            for (int k = 0; k < P_N / BLK; ++k) {
                int j = tid + k * BLK;
                if (!SC[j]) {
                    size_t idx = ((size_t)b * P_N + j) * G_M + cur;
                    float c = cd[idx] - 2.0f * gi[idx];
                    float red = ((minval + c) - ucur) - v[j];
                    if (red < shortest[j]) { shortest[j] = red; path[j] = (short)cur; }
                }
            }
            __syncthreads();
            float bv = 3.0e38f; int bi = P_N;
            #pragma unroll
            for (int k = 0; k < P_N / BLK; ++k) {
                int j = tid + k * BLK;
                lexmin(bv, bi, SC[j] ? BIGF : shortest[j], j);
            }
            #pragma unroll
            for (int off = 32; off > 0; off >>= 1) {
                float ov = __shfl_xor(bv, off, 64);
                int oi = __shfl_xor(bi, off, 64);
                lexmin(bv, bi, ov, oi);
            }
            if ((tid & 63) == 0) { rv[tid >> 6] = bv; ri[tid >> 6] = bi; }
            __syncthreads();
            if (tid == 0) {
                float mv = rv[0]; int mi = ri[0];
                for (int w = 1; w < WAVES; ++w) lexmin(mv, mi, rv[w], ri[w]);
                s_minval = mv; s_j = mi; SC[mi] = 1;
                int r = row4col[mi];
                if (r < 0) s_done = 1; else s_cur = r;
            }
            __syncthreads();
            minval = s_minval;
            if (s_done) { sink = s_j; break; }
            cur = s_cur;
        }
        if (tid < G_M) {
            if (tid == i) u[tid] += minval;
            else if (SR[tid]) {
                int c = col4row[tid]; if (c < 0) c = 0;
                u[tid] = (u[tid] + minval) - shortest[c];
            }
        }
        #pragma unroll
        for (int k = 0; k < P_N / BLK; ++k) {
            int j = tid + k * BLK;
            if (SC[j]) v[j] -= (minval - shortest[j]);
        }
        __syncthreads();
        if (tid == 0) {
            int j = sink;
            while (true) {
                int r = path[j];
                row4col[j] = (short)r;
                int jn = col4row[r];
                col4row[r] = (short)j;
                if (r == i) break;
                j = jn;
            }
        }
        __syncthreads();
    }
    float* out_inds = out + (size_t)b * P_N;
    float* out_mask = out + (size_t)B * P_N + (size_t)b * P_N;
    for (int j = tid; j < P_N; j += BLK) {
        int r = row4col[j];
        out_inds[j] = (r >= 0) ? (float)r : 0.0f;
        out_mask[j] = (r >= 0) ? 1.0f : 0.0f;
    }
}

extern "C" void kernel_launch(void* const* d_in, const int* in_sizes, int n_in,
                              void* d_out, int out_size, void* d_ws, size_t ws_size,
                              hipStream_t stream) {
    const float* cd = (const float*)d_in[0];
    const float* gi = (const float*)d_in[1];
    const int*   na = (const int*)d_in[2];
    float* out = (float*)d_out;
    const int B = in_sizes[2];   // 8

    const size_t costT_b = (size_t)B * G_M * P_N * sizeof(float);
    const size_t pm_b    = (size_t)B * NSTRIPE * G_M * sizeof(unsigned long long);
    auto al = [](size_t x) { return (x + 255) & ~(size_t)255; };
    const size_t o1 = al(costT_b);
    const size_t need = o1 + al(pm_b);

    if (ws_size >= need) {
        float* costT = (float*)d_ws;
        unsigned long long* pm = (unsigned long long*)((char*)d_ws + o1);
        cost_prep<<<dim3(B * NSTRIPE), 256, 0, stream>>>(cd, gi, na, costT, pm);
        lsa_solve<<<dim3(B), 256, 0, stream>>>(costT, pm, na, out, B);
    } else {
        lsa_full<<<dim3(B), BLK, 0, stream>>>(cd, gi, na, out, B);
    }
}